// Round 11
// baseline (241.436 us; speedup 1.0000x reference)
//
#include <hip/hip_runtime.h>
#include <hip/hip_bf16.h>
#include <math.h>

// Problem constants (PoseMixtureVAE)
#define N_BATCH 4096
#define FRAME   267
#define LATENT  32
#define HIDDEN  256
#define GATE_H  64
#define EXPERTS 6
// Kpads: [x|c]=534->544 (17 ksteps), [x|h]=523->544 (17), [z|c]=299->320 (10),
//        [z|h]=288 (9 exactly), gate hidden 64 (2)

typedef __hip_bfloat16 bf16;
typedef __bf16  bf16x8 __attribute__((ext_vector_type(8)));
typedef float   f32x4  __attribute__((ext_vector_type(4)));

__device__ __forceinline__ float eluf(float v) { return (v > 0.f) ? v : (expf(v) - 1.f); }

#define MFMA(a, b, p) __builtin_amdgcn_mfma_f32_16x16x32_bf16((a), (b), (p), 0, 0, 0)

struct WEnt { const float* src; bf16* dst; int K, M, Mtot, mOff, Ksteps, Mtiles, cum; };
struct WTab { WEnt e[10]; int total; };

// ---------------------------------------------------------------------------
// prep: weight repack (one 32x32 tile unit per block) + biasCat.
// ---------------------------------------------------------------------------
__global__ __launch_bounds__(256) void prep_kernel(
    const float* __restrict__ bmu, const float* __restrict__ blv,
    float* __restrict__ biasCat, WTab tab)
{
    const int tid = threadIdx.x, bid = blockIdx.x;
    if (bid == 0 && tid < 64)
        biasCat[tid] = (tid < 32) ? bmu[tid] : blv[tid - 32];

    __shared__ float tbuf[32][33];
    int i = 0;
    while (i < 9 && bid >= tab.e[i + 1].cum) ++i;
    const WEnt en = tab.e[i];
    const int t = bid - en.cum;
    const int perE = en.Ksteps * en.Mtiles;
    const int e = t / perE;
    const int rr = t - e * perE;
    const int mt = rr / en.Ksteps;
    const int ks = rr - mt * en.Ksteps;
    const int tx = tid & 31, ty = tid >> 5;
    const float* src = en.src + (size_t)e * en.K * en.M;
    #pragma unroll
    for (int i0 = 0; i0 < 32; i0 += 8) {
        const int k = ks * 32 + i0 + ty, m = mt * 32 + tx;
        tbuf[i0 + ty][tx] = (k < en.K && m < en.M) ? src[(size_t)k * en.M + m] : 0.f;
    }
    __syncthreads();
    bf16* dst = en.dst + ((size_t)(e * en.Ksteps + ks) * en.Mtot + en.mOff + mt * 32) * 32;
    #pragma unroll
    for (int i0 = 0; i0 < 32; i0 += 8)
        dst[(size_t)(i0 + ty) * 32 + tx] = __float2bfloat16(tbuf[tx][i0 + ty]);
}

// ---------------------------------------------------------------------------
// fused: ENTIRE network, 32 rows/block, 128 blocks, 1024 thr (16 waves).
// R2-R10 synthesis: the kernel is WEIGHT-STREAM-BANDWIDTH bound (~13 TB/s
// delivered; TLP x2 and load-depth x4 both flat). Fix: each B fragment now
// feeds TWO 16-row groups (rows r, r+16) -> total weight traffic halves
// (870 -> 435 MB). Registers stay under the 64-VGPR cap by (a) serial gate
// phase (no pe[] array), (b) incremental per-expert blend in MoE layers
// (live: p0,p1,acc0,acc1 = 16 VGPR).
// ---------------------------------------------------------------------------
__global__ __launch_bounds__(1024, 4) void fused_kernel(
    const float* __restrict__ x, const float* __restrict__ c,
    const float* __restrict__ eps,
    const bf16* __restrict__ We1, const float* __restrict__ eb1,
    const bf16* __restrict__ We2, const float* __restrict__ eb2,
    const bf16* __restrict__ Wml, const float* __restrict__ biasCat,
    const bf16* __restrict__ Wg0, const float* __restrict__ gb0,
    const bf16* __restrict__ Wg1, const float* __restrict__ gb1,
    const bf16* __restrict__ Wg2, const float* __restrict__ gb2,
    const bf16* __restrict__ W0, const float* __restrict__ b0,
    const bf16* __restrict__ W1, const float* __restrict__ b1,
    const bf16* __restrict__ W2, const float* __restrict__ b2,
    float* __restrict__ out_layer, float* __restrict__ out_mu,
    float* __restrict__ out_lv)
{
    __shared__ bf16  bufA[32 * 552];
    __shared__ bf16  bufB[32 * 552];
    __shared__ float sMLp[2][32 * 64];
    __shared__ bf16  sG1[32 * 72];
    __shared__ bf16  sG2[32 * 72];
    __shared__ float sLg[32 * 16];
    __shared__ float sCo[EXPERTS * 32];

    const int tid  = threadIdx.x;
    const int w    = tid >> 6, lane = tid & 63, ml = lane & 15, quad = lane >> 4;
    const int row0 = blockIdx.x * 32;

    // ---- Ph0: bufA = [x|c] bf16 (Kpad 544, zero pad). rows w, w+16. ----
    {
        #pragma unroll
        for (int rr = 0; rr < 2; ++rr) {
            const int r = w + rr * 16;
            const float* xr = x + (size_t)(row0 + r) * FRAME;
            const float* cr = c + (size_t)(row0 + r) * FRAME;
            #pragma unroll
            for (int j = 0; j < 9; ++j) {
                const int col = lane + j * 64;
                if (col < 544) {
                    float v = 0.f;
                    if (col < FRAME)          v = xr[col];
                    else if (col < 2 * FRAME) v = cr[col - FRAME];
                    bufA[r * 552 + col] = __float2bfloat16(v);
                }
            }
        }
    }
    __syncthreads();

    // ---- Ph1: h1 = elu([x|c] @ We1 + eb1), M=256 (16 tiles); bufB=[x|h1] ----
    {
        const int col = 16 * w + ml;
        const bf16* wq = We1 + (size_t)col * 32 + quad * 8;   // ks-stride 8192
        f32x4 a0 = (f32x4){0,0,0,0}, a1 = (f32x4){0,0,0,0};
        #pragma unroll
        for (int ks = 0; ks < 17; ++ks) {
            const bf16x8 b = *(const bf16x8*)(wq + (size_t)ks * 8192);
            a0 = MFMA(*(const bf16x8*)(bufA + ml * 552 + ks * 32 + quad * 8), b, a0);
            a1 = MFMA(*(const bf16x8*)(bufA + (16 + ml) * 552 + ks * 32 + quad * 8), b, a1);
        }
        const float bv = eb1[col];
        #pragma unroll
        for (int rg = 0; rg < 4; ++rg) {
            bufB[(quad * 4 + rg) * 552 + 267 + col]      = __float2bfloat16(eluf(a0[rg] + bv));
            bufB[(16 + quad * 4 + rg) * 552 + 267 + col] = __float2bfloat16(eluf(a1[rg] + bv));
        }
        // copy x -> bufB[0..266] rows w,w+16; zero pad 523..543
        #pragma unroll
        for (int rr = 0; rr < 2; ++rr) {
            const int r = w + rr * 16;
            #pragma unroll
            for (int j = 0; j < 5; ++j) {
                const int cc = lane + j * 64;
                if (cc < 267) bufB[r * 552 + cc] = bufA[r * 552 + cc];
            }
            if (lane < 21) bufB[r * 552 + 523 + lane] = __float2bfloat16(0.f);
        }
    }
    __syncthreads();

    // ---- Ph2: h2 = elu([x|h1] @ We2 + eb2) -> bufB in-place = [x|h2] ----
    {
        const int col = 16 * w + ml;
        const bf16* wq = We2 + (size_t)col * 32 + quad * 8;
        f32x4 a0 = (f32x4){0,0,0,0}, a1 = (f32x4){0,0,0,0};
        #pragma unroll
        for (int ks = 0; ks < 17; ++ks) {
            const bf16x8 b = *(const bf16x8*)(wq + (size_t)ks * 8192);
            a0 = MFMA(*(const bf16x8*)(bufB + ml * 552 + ks * 32 + quad * 8), b, a0);
            a1 = MFMA(*(const bf16x8*)(bufB + (16 + ml) * 552 + ks * 32 + quad * 8), b, a1);
        }
        __syncthreads();   // all reads of bufB done before overwrite
        const float bv = eb2[col];
        #pragma unroll
        for (int rg = 0; rg < 4; ++rg) {
            bufB[(quad * 4 + rg) * 552 + 267 + col]      = __float2bfloat16(eluf(a0[rg] + bv));
            bufB[(16 + quad * 4 + rg) * 552 + 267 + col] = __float2bfloat16(eluf(a1[rg] + bv));
        }
    }
    __syncthreads();

    // ---- Ph3: mu|lv partial-K: wave -> col tile (w&3), rg ((w>>2)&1), kg (w>>3)
    {
        const int ct = w & 3, rg = (w >> 2) & 1, kg = w >> 3;
        const int col = 16 * ct + ml;
        const int rbase = rg * 16;
        const int k0 = kg ? 9 : 0, k1 = kg ? 17 : 9;
        const bf16* wq = Wml + (size_t)col * 32 + quad * 8;   // ks-stride 2048
        f32x4 p = (f32x4){0,0,0,0};
        for (int ks = k0; ks < k1; ++ks)
            p = MFMA(*(const bf16x8*)(bufB + (rbase + ml) * 552 + ks * 32 + quad * 8),
                     *(const bf16x8*)(wq + (size_t)ks * 2048), p);
        #pragma unroll
        for (int rg2 = 0; rg2 < 4; ++rg2)
            sMLp[kg][(rbase + quad * 4 + rg2) * 64 + col] = p[rg2];
    }
    __syncthreads();

    // ---- Ph3b: z; bufB = [z|c] (Kpad 320); bufA[0..31] = z. 32x32 = 1024 thr
    {
        const int r = tid >> 5, l = tid & 31;
        const float m  = sMLp[0][r * 64 + l] + sMLp[1][r * 64 + l] + biasCat[l];
        const float lv = sMLp[0][r * 64 + 32 + l] + sMLp[1][r * 64 + 32 + l] + biasCat[32 + l];
        const int gi = (row0 + r) * LATENT + l;
        out_mu[gi] = m; out_lv[gi] = lv;
        const bf16 zb = __float2bfloat16(m + eps[gi] * expf(0.5f * lv));
        bufA[r * 552 + l] = zb;       // prefix of [z|dh1]
        bufB[r * 552 + l] = zb;       // prefix of [z|c]
        #pragma unroll
        for (int j = 0; j < 9; ++j) {
            const int col = 32 + l + j * 32;          // 32..319
            bf16 v = __float2bfloat16(0.f);
            if (col < 299) v = bufA[r * 552 + 267 + (col - 32)];   // c
            bufB[r * 552 + col] = v;
        }
    }
    __syncthreads();

    // ---- Ph4: gate chain (serial, small): g1 -> g2 -> logits -> softmax ----
    if (w < 4) {   // g1: K=320 (10 ks), M=64, both row groups
        const int col = 16 * w + ml;
        const bf16* gq = Wg0 + (size_t)col * 32 + quad * 8;   // ks-stride 2048
        f32x4 p0 = (f32x4){0,0,0,0}, p1 = (f32x4){0,0,0,0};
        #pragma unroll
        for (int ks = 0; ks < 10; ++ks) {
            const bf16x8 b = *(const bf16x8*)(gq + (size_t)ks * 2048);
            p0 = MFMA(*(const bf16x8*)(bufB + ml * 552 + ks * 32 + quad * 8), b, p0);
            p1 = MFMA(*(const bf16x8*)(bufB + (16 + ml) * 552 + ks * 32 + quad * 8), b, p1);
        }
        const float bv = gb0[col];
        #pragma unroll
        for (int rg = 0; rg < 4; ++rg) {
            sG1[(quad * 4 + rg) * 72 + col]      = __float2bfloat16(eluf(p0[rg] + bv));
            sG1[(16 + quad * 4 + rg) * 72 + col] = __float2bfloat16(eluf(p1[rg] + bv));
        }
    }
    __syncthreads();
    if (w < 4) {   // g2: K=64 (2 ks), M=64
        const int col = 16 * w + ml;
        const bf16* gq = Wg1 + (size_t)col * 32 + quad * 8;
        f32x4 p0 = (f32x4){0,0,0,0}, p1 = (f32x4){0,0,0,0};
        #pragma unroll
        for (int ks = 0; ks < 2; ++ks) {
            const bf16x8 b = *(const bf16x8*)(gq + (size_t)ks * 2048);
            p0 = MFMA(*(const bf16x8*)(sG1 + ml * 72 + ks * 32 + quad * 8), b, p0);
            p1 = MFMA(*(const bf16x8*)(sG1 + (16 + ml) * 72 + ks * 32 + quad * 8), b, p1);
        }
        const float bv = gb1[col];
        #pragma unroll
        for (int rg = 0; rg < 4; ++rg) {
            sG2[(quad * 4 + rg) * 72 + col]      = __float2bfloat16(eluf(p0[rg] + bv));
            sG2[(16 + quad * 4 + rg) * 72 + col] = __float2bfloat16(eluf(p1[rg] + bv));
        }
    }
    __syncthreads();
    if (w == 0) {  // logits: K=64 (2 ks), M=6 (Mtot 32)
        const bf16* gq = Wg2 + (size_t)ml * 32 + quad * 8;    // ks-stride 1024
        f32x4 p0 = (f32x4){0,0,0,0}, p1 = (f32x4){0,0,0,0};
        #pragma unroll
        for (int ks = 0; ks < 2; ++ks) {
            const bf16x8 b = *(const bf16x8*)(gq + (size_t)ks * 1024);
            p0 = MFMA(*(const bf16x8*)(sG2 + ml * 72 + ks * 32 + quad * 8), b, p0);
            p1 = MFMA(*(const bf16x8*)(sG2 + (16 + ml) * 72 + ks * 32 + quad * 8), b, p1);
        }
        const float bv = (ml < EXPERTS) ? gb2[ml] : 0.f;
        #pragma unroll
        for (int rg = 0; rg < 4; ++rg) {
            sLg[(quad * 4 + rg) * 16 + ml]      = p0[rg] + bv;
            sLg[(16 + quad * 4 + rg) * 16 + ml] = p1[rg] + bv;
        }
    }
    __syncthreads();
    if (tid < 32) {   // softmax per row
        float v[EXPERTS];
        float m = -1e30f;
        #pragma unroll
        for (int i = 0; i < EXPERTS; ++i) { v[i] = sLg[tid * 16 + i]; m = fmaxf(m, v[i]); }
        float s = 0.f;
        #pragma unroll
        for (int i = 0; i < EXPERTS; ++i) { v[i] = expf(v[i] - m); s += v[i]; }
        const float inv = 1.f / s;
        #pragma unroll
        for (int i = 0; i < EXPERTS; ++i) sCo[i * 32 + tid] = v[i] * inv;
    }
    __syncthreads();

    // ---- Ph5: dh1 = elu(moe([z|c], W0, b0)) -> bufA = [z|dh1] ----
    {
        const int col = 16 * w + ml;
        const bf16* wq = W0 + (size_t)col * 32 + quad * 8;    // (e*10+ks)-stride 8192
        f32x4 acc0 = (f32x4){0,0,0,0}, acc1 = (f32x4){0,0,0,0};
        #pragma unroll
        for (int e = 0; e < EXPERTS; ++e) {
            f32x4 p0 = (f32x4){0,0,0,0}, p1 = (f32x4){0,0,0,0};
            #pragma unroll
            for (int ks = 0; ks < 10; ++ks) {
                const bf16x8 b = *(const bf16x8*)(wq + (size_t)(e * 10 + ks) * 8192);
                p0 = MFMA(*(const bf16x8*)(bufB + ml * 552 + ks * 32 + quad * 8), b, p0);
                p1 = MFMA(*(const bf16x8*)(bufB + (16 + ml) * 552 + ks * 32 + quad * 8), b, p1);
            }
            const float bv = b0[e * 256 + col];
            #pragma unroll
            for (int rg = 0; rg < 4; ++rg) {
                acc0[rg] += sCo[e * 32 + quad * 4 + rg]      * (p0[rg] + bv);
                acc1[rg] += sCo[e * 32 + 16 + quad * 4 + rg] * (p1[rg] + bv);
            }
        }
        #pragma unroll
        for (int rg = 0; rg < 4; ++rg) {
            bufA[(quad * 4 + rg) * 552 + 32 + col]      = __float2bfloat16(eluf(acc0[rg]));
            bufA[(16 + quad * 4 + rg) * 552 + 32 + col] = __float2bfloat16(eluf(acc1[rg]));
        }
    }
    __syncthreads();

    // ---- Ph6: dh2 = elu(moe([z|dh1], W1, b1)) -> bufB = [z|dh2] ----
    {
        const int col = 16 * w + ml;
        const bf16* wq = W1 + (size_t)col * 32 + quad * 8;    // (e*9+ks)-stride 8192
        f32x4 acc0 = (f32x4){0,0,0,0}, acc1 = (f32x4){0,0,0,0};
        #pragma unroll
        for (int e = 0; e < EXPERTS; ++e) {
            f32x4 p0 = (f32x4){0,0,0,0}, p1 = (f32x4){0,0,0,0};
            #pragma unroll
            for (int ks = 0; ks < 9; ++ks) {
                const bf16x8 b = *(const bf16x8*)(wq + (size_t)(e * 9 + ks) * 8192);
                p0 = MFMA(*(const bf16x8*)(bufA + ml * 552 + ks * 32 + quad * 8), b, p0);
                p1 = MFMA(*(const bf16x8*)(bufA + (16 + ml) * 552 + ks * 32 + quad * 8), b, p1);
            }
            const float bv = b1[e * 256 + col];
            #pragma unroll
            for (int rg = 0; rg < 4; ++rg) {
                acc0[rg] += sCo[e * 32 + quad * 4 + rg]      * (p0[rg] + bv);
                acc1[rg] += sCo[e * 32 + 16 + quad * 4 + rg] * (p1[rg] + bv);
            }
        }
        // writes to bufB cols 32..287; bufB's last reads were in Ph5 (barrier above)
        #pragma unroll
        for (int rg = 0; rg < 4; ++rg) {
            bufB[(quad * 4 + rg) * 552 + 32 + col]      = __float2bfloat16(eluf(acc0[rg]));
            bufB[(16 + quad * 4 + rg) * 552 + 32 + col] = __float2bfloat16(eluf(acc1[rg]));
        }
    }
    __syncthreads();

    // ---- Ph7: out = moe([z|dh2], W2, b2), M=267 (17 tiles) -> global ----
    {
        for (int t = w; t < 17; t += 16) {
            const int col = 16 * t + ml;
            const bf16* wq = W2 + (size_t)col * 32 + quad * 8;   // (e*9+ks)-stride 10240
            f32x4 acc0 = (f32x4){0,0,0,0}, acc1 = (f32x4){0,0,0,0};
            #pragma unroll
            for (int e = 0; e < EXPERTS; ++e) {
                f32x4 p0 = (f32x4){0,0,0,0}, p1 = (f32x4){0,0,0,0};
                #pragma unroll
                for (int ks = 0; ks < 9; ++ks) {
                    const bf16x8 b = *(const bf16x8*)(wq + (size_t)(e * 9 + ks) * 10240);
                    p0 = MFMA(*(const bf16x8*)(bufB + ml * 552 + ks * 32 + quad * 8), b, p0);
                    p1 = MFMA(*(const bf16x8*)(bufB + (16 + ml) * 552 + ks * 32 + quad * 8), b, p1);
                }
                const float bv = (col < FRAME) ? b2[e * FRAME + col] : 0.f;
                #pragma unroll
                for (int rg = 0; rg < 4; ++rg) {
                    acc0[rg] += sCo[e * 32 + quad * 4 + rg]      * (p0[rg] + bv);
                    acc1[rg] += sCo[e * 32 + 16 + quad * 4 + rg] * (p1[rg] + bv);
                }
            }
            if (col < FRAME) {
                #pragma unroll
                for (int rg = 0; rg < 4; ++rg) {
                    out_layer[(size_t)(row0 + quad * 4 + rg) * FRAME + col]      = acc0[rg];
                    out_layer[(size_t)(row0 + 16 + quad * 4 + rg) * FRAME + col] = acc1[rg];
                }
            }
        }
    }
}

// ---------------------------------------------------------------------------
extern "C" void kernel_launch(void* const* d_in, const int* in_sizes, int n_in,
                              void* d_out, int out_size, void* d_ws, size_t ws_size,
                              hipStream_t stream) {
    const float* x       = (const float*)d_in[0];
    const float* c       = (const float*)d_in[1];
    const float* eps     = (const float*)d_in[2];
    const float* enc_w1  = (const float*)d_in[3];
    const float* enc_b1  = (const float*)d_in[4];
    const float* enc_w2  = (const float*)d_in[5];
    const float* enc_b2  = (const float*)d_in[6];
    const float* enc_wmu = (const float*)d_in[7];
    const float* enc_bmu = (const float*)d_in[8];
    const float* enc_wlv = (const float*)d_in[9];
    const float* enc_blv = (const float*)d_in[10];
    const float* g_w0    = (const float*)d_in[11];
    const float* g_b0    = (const float*)d_in[12];
    const float* g_w1    = (const float*)d_in[13];
    const float* g_b1    = (const float*)d_in[14];
    const float* g_w2    = (const float*)d_in[15];
    const float* g_b2    = (const float*)d_in[16];
    const float* w0      = (const float*)d_in[17];
    const float* b0      = (const float*)d_in[18];
    const float* w1      = (const float*)d_in[19];
    const float* b1      = (const float*)d_in[20];
    const float* w2      = (const float*)d_in[21];
    const float* b2      = (const float*)d_in[22];

    // output (f32): [layer (4096x267) | mu (4096x32) | logvar (4096x32)]
    float* out_layer = (float*)d_out;
    float* out_mu    = out_layer + (size_t)N_BATCH * FRAME;
    float* out_lv    = out_mu    + (size_t)N_BATCH * LATENT;

    // ---- workspace layout (16B-aligned): biasCat + repacked weights only ----
    char* p = (char*)d_ws;
    float* biasCat = (float*)p;  p += 64 * 4;
    bf16* Wt_e1 = (bf16*)p;      p += (size_t)17 * 256 * 32 * 2;
    bf16* Wt_e2 = (bf16*)p;      p += (size_t)17 * 256 * 32 * 2;
    bf16* Wt_ml = (bf16*)p;      p += (size_t)17 * 64 * 32 * 2;
    bf16* Wt_g0 = (bf16*)p;      p += (size_t)10 * 64 * 32 * 2;
    bf16* Wt_g1 = (bf16*)p;      p += (size_t)2 * 64 * 32 * 2;
    bf16* Wt_g2 = (bf16*)p;      p += (size_t)2 * 32 * 32 * 2;
    bf16* Wt_w0 = (bf16*)p;      p += (size_t)EXPERTS * 10 * 256 * 32 * 2;
    bf16* Wt_w1 = (bf16*)p;      p += (size_t)EXPERTS * 9 * 256 * 32 * 2;
    bf16* Wt_w2 = (bf16*)p;      p += (size_t)EXPERTS * 9 * 320 * 32 * 2;

    WTab tab;
    int cum = 0, n = 0;
    auto add = [&](const float* src, bf16* dst, int K, int M, int Mtot, int mOff, int E) {
        int Ksteps;
        if (K == 534 || K == 523) Ksteps = 17;
        else if (K == 299) Ksteps = 10;
        else if (K == 288) Ksteps = 9;
        else Ksteps = 2;   // K=64
        const int Mtiles = (M + 31) / 32;
        tab.e[n] = {src, dst, K, M, Mtot, mOff, Ksteps, Mtiles, cum};
        cum += E * Ksteps * Mtiles;
        ++n;
    };
    add(enc_w1,  Wt_e1, 534, 256, 256, 0, 1);
    add(enc_w2,  Wt_e2, 523, 256, 256, 0, 1);
    add(enc_wmu, Wt_ml, 523, 32, 64, 0, 1);
    add(enc_wlv, Wt_ml, 523, 32, 64, 32, 1);
    add(g_w0,    Wt_g0, 299, 64, 64, 0, 1);
    add(g_w1,    Wt_g1, 64, 64, 64, 0, 1);
    add(g_w2,    Wt_g2, 64, 6, 32, 0, 1);
    add(w0,      Wt_w0, 299, 256, 256, 0, EXPERTS);
    add(w1,      Wt_w1, 288, 256, 256, 0, EXPERTS);
    add(w2,      Wt_w2, 288, 267, 320, 0, EXPERTS);
    tab.total = cum;

    // 0) prep: weight repack (cum blocks) + biasCat
    prep_kernel<<<dim3(cum), dim3(256), 0, stream>>>(enc_bmu, enc_blv, biasCat, tab);

    // 1) fully fused network: 128 blocks x 1024 threads (32 rows/block)
    fused_kernel<<<dim3(N_BATCH / 32), dim3(1024), 0, stream>>>(
        x, c, eps,
        Wt_e1, enc_b1, Wt_e2, enc_b2, Wt_ml, biasCat,
        Wt_g0, g_b0, Wt_g1, g_b1, Wt_g2, g_b2,
        Wt_w0, b0, Wt_w1, b1, Wt_w2, b2,
        out_layer, out_mu, out_lv);
}

// Round 12
// 182.801 us; speedup vs baseline: 1.3208x; 1.3208x over previous
//
#include <hip/hip_runtime.h>
#include <hip/hip_bf16.h>
#include <math.h>

// Problem constants (PoseMixtureVAE)
#define N_BATCH 4096
#define FRAME   267
#define LATENT  32
#define HIDDEN  256
#define GATE_H  64
#define EXPERTS 6
// Kpads: [x|c]=534->544 (17 ksteps), [x|h]=523->544 (17), [z|c]=299->320 (10),
//        [z|h]=288 (9 exactly), gate hidden 64 (2)

typedef __hip_bfloat16 bf16;
typedef __bf16  bf16x8 __attribute__((ext_vector_type(8)));
typedef float   f32x4  __attribute__((ext_vector_type(4)));

__device__ __forceinline__ float eluf(float v) { return (v > 0.f) ? v : (expf(v) - 1.f); }

#define MFMA(a, b, p) __builtin_amdgcn_mfma_f32_16x16x32_bf16((a), (b), (p), 0, 0, 0)

struct WEnt { const float* src; bf16* dst; int K, M, Mtot, mOff, Ksteps, Mtiles, cum; };
struct WTab { WEnt e[10]; int total; };

// ---------------------------------------------------------------------------
// prep: weight repack (one 32x32 tile unit per block) + biasCat.
// ---------------------------------------------------------------------------
__global__ __launch_bounds__(256) void prep_kernel(
    const float* __restrict__ bmu, const float* __restrict__ blv,
    float* __restrict__ biasCat, WTab tab)
{
    const int tid = threadIdx.x, bid = blockIdx.x;
    if (bid == 0 && tid < 64)
        biasCat[tid] = (tid < 32) ? bmu[tid] : blv[tid - 32];

    __shared__ float tbuf[32][33];
    int i = 0;
    while (i < 9 && bid >= tab.e[i + 1].cum) ++i;
    const WEnt en = tab.e[i];
    const int t = bid - en.cum;
    const int perE = en.Ksteps * en.Mtiles;
    const int e = t / perE;
    const int rr = t - e * perE;
    const int mt = rr / en.Ksteps;
    const int ks = rr - mt * en.Ksteps;
    const int tx = tid & 31, ty = tid >> 5;
    const float* src = en.src + (size_t)e * en.K * en.M;
    #pragma unroll
    for (int i0 = 0; i0 < 32; i0 += 8) {
        const int k = ks * 32 + i0 + ty, m = mt * 32 + tx;
        tbuf[i0 + ty][tx] = (k < en.K && m < en.M) ? src[(size_t)k * en.M + m] : 0.f;
    }
    __syncthreads();
    bf16* dst = en.dst + ((size_t)(e * en.Ksteps + ks) * en.Mtot + en.mOff + mt * 32) * 32;
    #pragma unroll
    for (int i0 = 0; i0 < 32; i0 += 8)
        dst[(size_t)(i0 + ty) * 32 + tx] = __float2bfloat16(tbuf[tx][i0 + ty]);
}

// ---------------------------------------------------------------------------
// fused: ENTIRE network, 16 rows/block, 256 blocks x 512 threads (8 waves)
// -> 2 blocks/CU. R11 falsified chip-level BW bound; model is per-CU
// serial-sum of {vmem-return, LDS A-reads, MFMA} with lockstep barriers.
// Fixes: (a) TWO independent blocks per CU — barrier/gate phases of one
// block overlap MoE streams of the other; (b) col-RF=2 per wave sharing
// ONE A-fragment ds_read across 2 MFMAs (halves LDS A-traffic);
// (c) register-light phases everywhere (serial gate, incremental blend)
// so the 64-VGPR allocation never spills.
// ---------------------------------------------------------------------------
__global__ __launch_bounds__(512, 4) void fused_kernel(
    const float* __restrict__ x, const float* __restrict__ c,
    const float* __restrict__ eps,
    const bf16* __restrict__ We1, const float* __restrict__ eb1,
    const bf16* __restrict__ We2, const float* __restrict__ eb2,
    const bf16* __restrict__ Wml, const float* __restrict__ biasCat,
    const bf16* __restrict__ Wg0, const float* __restrict__ gb0,
    const bf16* __restrict__ Wg1, const float* __restrict__ gb1,
    const bf16* __restrict__ Wg2, const float* __restrict__ gb2,
    const bf16* __restrict__ W0, const float* __restrict__ b0,
    const bf16* __restrict__ W1, const float* __restrict__ b1,
    const bf16* __restrict__ W2, const float* __restrict__ b2,
    float* __restrict__ out_layer, float* __restrict__ out_mu,
    float* __restrict__ out_lv)
{
    __shared__ bf16  bufA[16 * 552];
    __shared__ bf16  bufB[16 * 552];
    __shared__ float sMLp[2][16 * 64];
    __shared__ bf16  sG1[16 * 72];
    __shared__ bf16  sG2[16 * 72];
    __shared__ float sLg[16 * 16];
    __shared__ float sCo[EXPERTS * 16];

    const int tid  = threadIdx.x;
    const int w    = tid >> 6, lane = tid & 63, ml = lane & 15, quad = lane >> 4;
    const int row0 = blockIdx.x * 16;

    // ---- Ph0: bufA = [x|c] bf16 (Kpad 544, zero 534..543). rows w, w+8 ----
    {
        #pragma unroll
        for (int rr = 0; rr < 2; ++rr) {
            const int r = w + rr * 8;
            const float* xr = x + (size_t)(row0 + r) * FRAME;
            const float* cr = c + (size_t)(row0 + r) * FRAME;
            #pragma unroll
            for (int j = 0; j < 9; ++j) {
                const int col = lane + j * 64;
                if (col < 544) {
                    float v = 0.f;
                    if (col < FRAME)          v = xr[col];
                    else if (col < 2 * FRAME) v = cr[col - FRAME];
                    bufA[r * 552 + col] = __float2bfloat16(v);
                }
            }
        }
    }
    __syncthreads();

    // ---- Ph1: h1 = elu([x|c] @ We1 + eb1), M=256; wave w -> cols 32w+ml, +16
    {
        const int col0 = 32 * w + ml;
        const bf16* wq0 = We1 + (size_t)col0 * 32 + quad * 8;   // ks-stride 8192
        const bf16* wq1 = wq0 + 16 * 32;
        f32x4 a0 = (f32x4){0,0,0,0}, a1 = (f32x4){0,0,0,0};
        #pragma unroll
        for (int ks = 0; ks < 17; ++ks) {
            const bf16x8 a = *(const bf16x8*)(bufA + ml * 552 + ks * 32 + quad * 8);
            a0 = MFMA(a, *(const bf16x8*)(wq0 + (size_t)ks * 8192), a0);
            a1 = MFMA(a, *(const bf16x8*)(wq1 + (size_t)ks * 8192), a1);
        }
        const float bv0 = eb1[col0], bv1 = eb1[col0 + 16];
        #pragma unroll
        for (int rg = 0; rg < 4; ++rg) {
            bufB[(quad * 4 + rg) * 552 + 267 + col0]      = __float2bfloat16(eluf(a0[rg] + bv0));
            bufB[(quad * 4 + rg) * 552 + 267 + col0 + 16] = __float2bfloat16(eluf(a1[rg] + bv1));
        }
        // copy x -> bufB[0..266] rows w, w+8; zero pad 523..543
        #pragma unroll
        for (int rr = 0; rr < 2; ++rr) {
            const int r = w + rr * 8;
            #pragma unroll
            for (int j = 0; j < 5; ++j) {
                const int cc = lane + j * 64;
                if (cc < 267) bufB[r * 552 + cc] = bufA[r * 552 + cc];
            }
            if (lane < 21) bufB[r * 552 + 523 + lane] = __float2bfloat16(0.f);
        }
    }
    __syncthreads();

    // ---- Ph2: h2 = elu([x|h1] @ We2 + eb2) -> bufB in-place = [x|h2] ----
    {
        const int col0 = 32 * w + ml;
        const bf16* wq0 = We2 + (size_t)col0 * 32 + quad * 8;
        const bf16* wq1 = wq0 + 16 * 32;
        f32x4 a0 = (f32x4){0,0,0,0}, a1 = (f32x4){0,0,0,0};
        #pragma unroll
        for (int ks = 0; ks < 17; ++ks) {
            const bf16x8 a = *(const bf16x8*)(bufB + ml * 552 + ks * 32 + quad * 8);
            a0 = MFMA(a, *(const bf16x8*)(wq0 + (size_t)ks * 8192), a0);
            a1 = MFMA(a, *(const bf16x8*)(wq1 + (size_t)ks * 8192), a1);
        }
        __syncthreads();   // all reads of bufB done before overwrite
        const float bv0 = eb2[col0], bv1 = eb2[col0 + 16];
        #pragma unroll
        for (int rg = 0; rg < 4; ++rg) {
            bufB[(quad * 4 + rg) * 552 + 267 + col0]      = __float2bfloat16(eluf(a0[rg] + bv0));
            bufB[(quad * 4 + rg) * 552 + 267 + col0 + 16] = __float2bfloat16(eluf(a1[rg] + bv1));
        }
    }
    __syncthreads();

    // ---- Ph3: mu|lv partial-K: wave -> col tile (w&3), k-group (w>>2) ----
    {
        const int ct = w & 3, kg = w >> 2;               // kg in {0,1}
        const int col = 16 * ct + ml;
        const int k0 = kg ? 9 : 0, k1 = kg ? 17 : 9;
        const bf16* wq = Wml + (size_t)col * 32 + quad * 8;   // ks-stride 2048
        f32x4 p = (f32x4){0,0,0,0};
        for (int ks = k0; ks < k1; ++ks)
            p = MFMA(*(const bf16x8*)(bufB + ml * 552 + ks * 32 + quad * 8),
                     *(const bf16x8*)(wq + (size_t)ks * 2048), p);
        #pragma unroll
        for (int rg = 0; rg < 4; ++rg)
            sMLp[kg][(quad * 4 + rg) * 64 + col] = p[rg];
    }
    __syncthreads();

    // ---- Ph3b: z; bufB = [z|c] (Kpad 320); bufA[0..31] = z. 512 thr = 16x32
    {
        const int r = tid >> 5, l = tid & 31;
        const float m  = sMLp[0][r * 64 + l] + sMLp[1][r * 64 + l] + biasCat[l];
        const float lv = sMLp[0][r * 64 + 32 + l] + sMLp[1][r * 64 + 32 + l] + biasCat[32 + l];
        const int gi = (row0 + r) * LATENT + l;
        out_mu[gi] = m; out_lv[gi] = lv;
        const bf16 zb = __float2bfloat16(m + eps[gi] * expf(0.5f * lv));
        bufA[r * 552 + l] = zb;       // prefix of [z|dh1]
        bufB[r * 552 + l] = zb;       // prefix of [z|c]
        #pragma unroll
        for (int j = 0; j < 9; ++j) {
            const int col = 32 + l + j * 32;          // 32..319
            bf16 v = __float2bfloat16(0.f);
            if (col < 299) v = bufA[r * 552 + 267 + (col - 32)];   // c
            bufB[r * 552 + col] = v;
        }
    }
    __syncthreads();

    // ---- Ph4: gate chain (serial; overlaps the OTHER block's MoE) ----
    if (w < 4) {   // g1: K=320 (10 ks), M=64
        const int col = 16 * w + ml;
        const bf16* gq = Wg0 + (size_t)col * 32 + quad * 8;   // ks-stride 2048
        f32x4 p = (f32x4){0,0,0,0};
        #pragma unroll
        for (int ks = 0; ks < 10; ++ks)
            p = MFMA(*(const bf16x8*)(bufB + ml * 552 + ks * 32 + quad * 8),
                     *(const bf16x8*)(gq + (size_t)ks * 2048), p);
        const float bv = gb0[col];
        #pragma unroll
        for (int rg = 0; rg < 4; ++rg)
            sG1[(quad * 4 + rg) * 72 + col] = __float2bfloat16(eluf(p[rg] + bv));
    }
    __syncthreads();
    if (w < 4) {   // g2: K=64 (2 ks), M=64
        const int col = 16 * w + ml;
        const bf16* gq = Wg1 + (size_t)col * 32 + quad * 8;
        f32x4 p = (f32x4){0,0,0,0};
        #pragma unroll
        for (int ks = 0; ks < 2; ++ks)
            p = MFMA(*(const bf16x8*)(sG1 + ml * 72 + ks * 32 + quad * 8),
                     *(const bf16x8*)(gq + (size_t)ks * 2048), p);
        const float bv = gb1[col];
        #pragma unroll
        for (int rg = 0; rg < 4; ++rg)
            sG2[(quad * 4 + rg) * 72 + col] = __float2bfloat16(eluf(p[rg] + bv));
    }
    __syncthreads();
    if (w == 0) {  // logits: K=64 (2 ks), M=6 (Mtot 32)
        const bf16* gq = Wg2 + (size_t)ml * 32 + quad * 8;    // ks-stride 1024
        f32x4 p = (f32x4){0,0,0,0};
        #pragma unroll
        for (int ks = 0; ks < 2; ++ks)
            p = MFMA(*(const bf16x8*)(sG2 + ml * 72 + ks * 32 + quad * 8),
                     *(const bf16x8*)(gq + (size_t)ks * 1024), p);
        const float bv = (ml < EXPERTS) ? gb2[ml] : 0.f;
        #pragma unroll
        for (int rg = 0; rg < 4; ++rg)
            sLg[(quad * 4 + rg) * 16 + ml] = p[rg] + bv;
    }
    __syncthreads();
    if (tid < 16) {   // softmax per row
        float v[EXPERTS];
        float m = -1e30f;
        #pragma unroll
        for (int i = 0; i < EXPERTS; ++i) { v[i] = sLg[tid * 16 + i]; m = fmaxf(m, v[i]); }
        float s = 0.f;
        #pragma unroll
        for (int i = 0; i < EXPERTS; ++i) { v[i] = expf(v[i] - m); s += v[i]; }
        const float inv = 1.f / s;
        #pragma unroll
        for (int i = 0; i < EXPERTS; ++i) sCo[i * 16 + tid] = v[i] * inv;
    }
    __syncthreads();

    // ---- Ph5: dh1 = elu(moe([z|c], W0, b0)) -> bufA = [z|dh1] ----
    {
        const int col0 = 32 * w + ml;
        const bf16* wq0 = W0 + (size_t)col0 * 32 + quad * 8;   // (e*10+ks)-stride 8192
        const bf16* wq1 = wq0 + 16 * 32;
        f32x4 acc0 = (f32x4){0,0,0,0}, acc1 = (f32x4){0,0,0,0};
        #pragma unroll
        for (int e = 0; e < EXPERTS; ++e) {
            f32x4 p0 = (f32x4){0,0,0,0}, p1 = (f32x4){0,0,0,0};
            #pragma unroll
            for (int ks = 0; ks < 10; ++ks) {
                const bf16x8 a = *(const bf16x8*)(bufB + ml * 552 + ks * 32 + quad * 8);
                p0 = MFMA(a, *(const bf16x8*)(wq0 + (size_t)(e * 10 + ks) * 8192), p0);
                p1 = MFMA(a, *(const bf16x8*)(wq1 + (size_t)(e * 10 + ks) * 8192), p1);
            }
            const float bv0 = b0[e * 256 + col0], bv1 = b0[e * 256 + col0 + 16];
            #pragma unroll
            for (int rg = 0; rg < 4; ++rg) {
                const float cf = sCo[e * 16 + quad * 4 + rg];
                acc0[rg] += cf * (p0[rg] + bv0);
                acc1[rg] += cf * (p1[rg] + bv1);
            }
        }
        #pragma unroll
        for (int rg = 0; rg < 4; ++rg) {
            bufA[(quad * 4 + rg) * 552 + 32 + col0]      = __float2bfloat16(eluf(acc0[rg]));
            bufA[(quad * 4 + rg) * 552 + 32 + col0 + 16] = __float2bfloat16(eluf(acc1[rg]));
        }
    }
    __syncthreads();

    // ---- Ph6: dh2 = elu(moe([z|dh1], W1, b1)) -> bufB = [z|dh2] ----
    {
        const int col0 = 32 * w + ml;
        const bf16* wq0 = W1 + (size_t)col0 * 32 + quad * 8;   // (e*9+ks)-stride 8192
        const bf16* wq1 = wq0 + 16 * 32;
        f32x4 acc0 = (f32x4){0,0,0,0}, acc1 = (f32x4){0,0,0,0};
        #pragma unroll
        for (int e = 0; e < EXPERTS; ++e) {
            f32x4 p0 = (f32x4){0,0,0,0}, p1 = (f32x4){0,0,0,0};
            #pragma unroll
            for (int ks = 0; ks < 9; ++ks) {
                const bf16x8 a = *(const bf16x8*)(bufA + ml * 552 + ks * 32 + quad * 8);
                p0 = MFMA(a, *(const bf16x8*)(wq0 + (size_t)(e * 9 + ks) * 8192), p0);
                p1 = MFMA(a, *(const bf16x8*)(wq1 + (size_t)(e * 9 + ks) * 8192), p1);
            }
            const float bv0 = b1[e * 256 + col0], bv1 = b1[e * 256 + col0 + 16];
            #pragma unroll
            for (int rg = 0; rg < 4; ++rg) {
                const float cf = sCo[e * 16 + quad * 4 + rg];
                acc0[rg] += cf * (p0[rg] + bv0);
                acc1[rg] += cf * (p1[rg] + bv1);
            }
        }
        // writes to bufB; its last reads were before the Ph5-end barrier
        #pragma unroll
        for (int rg = 0; rg < 4; ++rg) {
            bufB[(quad * 4 + rg) * 552 + 32 + col0]      = __float2bfloat16(eluf(acc0[rg]));
            bufB[(quad * 4 + rg) * 552 + 32 + col0 + 16] = __float2bfloat16(eluf(acc1[rg]));
        }
    }
    __syncthreads();

    // ---- Ph7: out = moe([z|dh2], W2, b2), M=267 (17 tiles) -> global ----
    {
        for (int t = w; t < 17; t += 8) {
            const int col = 16 * t + ml;
            const bf16* wq = W2 + (size_t)col * 32 + quad * 8;   // (e*9+ks)-stride 10240
            f32x4 acc = (f32x4){0,0,0,0};
            #pragma unroll
            for (int e = 0; e < EXPERTS; ++e) {
                f32x4 p = (f32x4){0,0,0,0};
                #pragma unroll
                for (int ks = 0; ks < 9; ++ks)
                    p = MFMA(*(const bf16x8*)(bufB + ml * 552 + ks * 32 + quad * 8),
                             *(const bf16x8*)(wq + (size_t)(e * 9 + ks) * 10240), p);
                const float bv = (col < FRAME) ? b2[e * FRAME + col] : 0.f;
                #pragma unroll
                for (int rg = 0; rg < 4; ++rg)
                    acc[rg] += sCo[e * 16 + quad * 4 + rg] * (p[rg] + bv);
            }
            if (col < FRAME) {
                #pragma unroll
                for (int rg = 0; rg < 4; ++rg)
                    out_layer[(size_t)(row0 + quad * 4 + rg) * FRAME + col] = acc[rg];
            }
        }
    }
}

// ---------------------------------------------------------------------------
extern "C" void kernel_launch(void* const* d_in, const int* in_sizes, int n_in,
                              void* d_out, int out_size, void* d_ws, size_t ws_size,
                              hipStream_t stream) {
    const float* x       = (const float*)d_in[0];
    const float* c       = (const float*)d_in[1];
    const float* eps     = (const float*)d_in[2];
    const float* enc_w1  = (const float*)d_in[3];
    const float* enc_b1  = (const float*)d_in[4];
    const float* enc_w2  = (const float*)d_in[5];
    const float* enc_b2  = (const float*)d_in[6];
    const float* enc_wmu = (const float*)d_in[7];
    const float* enc_bmu = (const float*)d_in[8];
    const float* enc_wlv = (const float*)d_in[9];
    const float* enc_blv = (const float*)d_in[10];
    const float* g_w0    = (const float*)d_in[11];
    const float* g_b0    = (const float*)d_in[12];
    const float* g_w1    = (const float*)d_in[13];
    const float* g_b1    = (const float*)d_in[14];
    const float* g_w2    = (const float*)d_in[15];
    const float* g_b2    = (const float*)d_in[16];
    const float* w0      = (const float*)d_in[17];
    const float* b0      = (const float*)d_in[18];
    const float* w1      = (const float*)d_in[19];
    const float* b1      = (const float*)d_in[20];
    const float* w2      = (const float*)d_in[21];
    const float* b2      = (const float*)d_in[22];

    // output (f32): [layer (4096x267) | mu (4096x32) | logvar (4096x32)]
    float* out_layer = (float*)d_out;
    float* out_mu    = out_layer + (size_t)N_BATCH * FRAME;
    float* out_lv    = out_mu    + (size_t)N_BATCH * LATENT;

    // ---- workspace layout (16B-aligned): biasCat + repacked weights only ----
    char* p = (char*)d_ws;
    float* biasCat = (float*)p;  p += 64 * 4;
    bf16* Wt_e1 = (bf16*)p;      p += (size_t)17 * 256 * 32 * 2;
    bf16* Wt_e2 = (bf16*)p;      p += (size_t)17 * 256 * 32 * 2;
    bf16* Wt_ml = (bf16*)p;      p += (size_t)17 * 64 * 32 * 2;
    bf16* Wt_g0 = (bf16*)p;      p += (size_t)10 * 64 * 32 * 2;
    bf16* Wt_g1 = (bf16*)p;      p += (size_t)2 * 64 * 32 * 2;
    bf16* Wt_g2 = (bf16*)p;      p += (size_t)2 * 32 * 32 * 2;
    bf16* Wt_w0 = (bf16*)p;      p += (size_t)EXPERTS * 10 * 256 * 32 * 2;
    bf16* Wt_w1 = (bf16*)p;      p += (size_t)EXPERTS * 9 * 256 * 32 * 2;
    bf16* Wt_w2 = (bf16*)p;      p += (size_t)EXPERTS * 9 * 320 * 32 * 2;

    WTab tab;
    int cum = 0, n = 0;
    auto add = [&](const float* src, bf16* dst, int K, int M, int Mtot, int mOff, int E) {
        int Ksteps;
        if (K == 534 || K == 523) Ksteps = 17;
        else if (K == 299) Ksteps = 10;
        else if (K == 288) Ksteps = 9;
        else Ksteps = 2;   // K=64
        const int Mtiles = (M + 31) / 32;
        tab.e[n] = {src, dst, K, M, Mtot, mOff, Ksteps, Mtiles, cum};
        cum += E * Ksteps * Mtiles;
        ++n;
    };
    add(enc_w1,  Wt_e1, 534, 256, 256, 0, 1);
    add(enc_w2,  Wt_e2, 523, 256, 256, 0, 1);
    add(enc_wmu, Wt_ml, 523, 32, 64, 0, 1);
    add(enc_wlv, Wt_ml, 523, 32, 64, 32, 1);
    add(g_w0,    Wt_g0, 299, 64, 64, 0, 1);
    add(g_w1,    Wt_g1, 64, 64, 64, 0, 1);
    add(g_w2,    Wt_g2, 64, 6, 32, 0, 1);
    add(w0,      Wt_w0, 299, 256, 256, 0, EXPERTS);
    add(w1,      Wt_w1, 288, 256, 256, 0, EXPERTS);
    add(w2,      Wt_w2, 288, 267, 320, 0, EXPERTS);
    tab.total = cum;

    // 0) prep: weight repack (cum blocks) + biasCat
    prep_kernel<<<dim3(cum), dim3(256), 0, stream>>>(enc_bmu, enc_blv, biasCat, tab);

    // 1) fully fused network: 256 blocks x 512 threads (2 blocks/CU, 8 waves)
    fused_kernel<<<dim3(N_BATCH / 16), dim3(512), 0, stream>>>(
        x, c, eps,
        Wt_e1, enc_b1, Wt_e2, enc_b2, Wt_ml, biasCat,
        Wt_g0, g_b0, Wt_g1, g_b1, Wt_g2, g_b2,
        Wt_w0, b0, Wt_w1, b1, Wt_w2, b2,
        out_layer, out_mu, out_lv);
}

// Round 13
// 164.348 us; speedup vs baseline: 1.4691x; 1.1123x over previous
//
#include <hip/hip_runtime.h>
#include <hip/hip_bf16.h>
#include <math.h>

// Problem constants (PoseMixtureVAE)
#define N_BATCH 4096
#define FRAME   267
#define LATENT  32
#define HIDDEN  256
#define GATE_H  64
#define EXPERTS 6
// Kpads: [x|c]=534->544 (17 ksteps), [x|h]=523->544 (17), [z|c]=299->320 (10),
//        [z|h]=288 (9 exactly), gate hidden 64 (2)

typedef __hip_bfloat16 bf16;
typedef __bf16  bf16x8 __attribute__((ext_vector_type(8)));
typedef float   f32x4  __attribute__((ext_vector_type(4)));

__device__ __forceinline__ float eluf(float v) { return (v > 0.f) ? v : (expf(v) - 1.f); }

#define MFMA(a, b, p) __builtin_amdgcn_mfma_f32_16x16x32_bf16((a), (b), (p), 0, 0, 0)

struct WEnt { const float* src; bf16* dst; int K, M, Mtot, mOff, Ksteps, Mtiles, cum; };
struct WTab { WEnt e[10]; int total; };

// ---------------------------------------------------------------------------
// prep: weight repack (one 32x32 tile unit per block) + biasCat.
// ---------------------------------------------------------------------------
__global__ __launch_bounds__(256) void prep_kernel(
    const float* __restrict__ bmu, const float* __restrict__ blv,
    float* __restrict__ biasCat, WTab tab)
{
    const int tid = threadIdx.x, bid = blockIdx.x;
    if (bid == 0 && tid < 64)
        biasCat[tid] = (tid < 32) ? bmu[tid] : blv[tid - 32];

    __shared__ float tbuf[32][33];
    int i = 0;
    while (i < 9 && bid >= tab.e[i + 1].cum) ++i;
    const WEnt en = tab.e[i];
    const int t = bid - en.cum;
    const int perE = en.Ksteps * en.Mtiles;
    const int e = t / perE;
    const int rr = t - e * perE;
    const int mt = rr / en.Ksteps;
    const int ks = rr - mt * en.Ksteps;
    const int tx = tid & 31, ty = tid >> 5;
    const float* src = en.src + (size_t)e * en.K * en.M;
    #pragma unroll
    for (int i0 = 0; i0 < 32; i0 += 8) {
        const int k = ks * 32 + i0 + ty, m = mt * 32 + tx;
        tbuf[i0 + ty][tx] = (k < en.K && m < en.M) ? src[(size_t)k * en.M + m] : 0.f;
    }
    __syncthreads();
    bf16* dst = en.dst + ((size_t)(e * en.Ksteps + ks) * en.Mtot + en.mOff + mt * 32) * 32;
    #pragma unroll
    for (int i0 = 0; i0 < 32; i0 += 8)
        dst[(size_t)(i0 + ty) * 32 + tx] = __float2bfloat16(tbuf[tx][i0 + ty]);
}

// ---------------------------------------------------------------------------
// fused: ENTIRE network, 16 rows/block, 256 blocks (1/CU), 1024 thr (16 waves).
// R13: MoE phases use ks-OUTER / expert-INNER loops: one ds_read A-fragment
// feeds 6 MFMAs (6x fewer LDS reads), and the 6 independent B-loads per
// iteration are REQUIRED to be live simultaneously -> the min-liveness
// scheduler itself must keep 6 loads in flight (the depth R4-R9 couldn't
// get). Live regs ~55 < the 64-VGPR allocation -> no spills.
// ---------------------------------------------------------------------------
__global__ __launch_bounds__(1024, 4) void fused_kernel(
    const float* __restrict__ x, const float* __restrict__ c,
    const float* __restrict__ eps,
    const bf16* __restrict__ We1, const float* __restrict__ eb1,
    const bf16* __restrict__ We2, const float* __restrict__ eb2,
    const bf16* __restrict__ Wml, const float* __restrict__ biasCat,
    const bf16* __restrict__ Wg0, const float* __restrict__ gb0,
    const bf16* __restrict__ Wg1, const float* __restrict__ gb1,
    const bf16* __restrict__ Wg2, const float* __restrict__ gb2,
    const bf16* __restrict__ W0, const float* __restrict__ b0,
    const bf16* __restrict__ W1, const float* __restrict__ b1,
    const bf16* __restrict__ W2, const float* __restrict__ b2,
    float* __restrict__ out_layer, float* __restrict__ out_mu,
    float* __restrict__ out_lv)
{
    __shared__ bf16  bufA[16 * 552];
    __shared__ bf16  bufB[16 * 552];
    __shared__ float sMLp[4][16 * 64];
    __shared__ bf16  sG1[16 * 72];
    __shared__ bf16  sG2[16 * 72];
    __shared__ float sLg[16 * 16];
    __shared__ float sCo[EXPERTS * 16];

    const int tid  = threadIdx.x;
    const int w    = tid >> 6, lane = tid & 63, ml = lane & 15, quad = lane >> 4;
    const int row0 = blockIdx.x * 16;

    // ---- Ph0: bufA = [x|c] bf16 (Kpad 544, zero 534..543). row = w. ----
    {
        const float* xr = x + (size_t)(row0 + w) * FRAME;
        const float* cr = c + (size_t)(row0 + w) * FRAME;
        #pragma unroll
        for (int j = 0; j < 9; ++j) {
            const int col = lane + j * 64;
            if (col < 544) {
                float v = 0.f;
                if (col < FRAME)          v = xr[col];
                else if (col < 2 * FRAME) v = cr[col - FRAME];
                bufA[w * 552 + col] = __float2bfloat16(v);
            }
        }
    }
    __syncthreads();

    // ---- Ph1: h1 = elu([x|c] @ We1 + eb1), M=256 (16 tiles); bufB=[x|h1] ----
    {
        const int col = 16 * w + ml;
        const bf16* wq = We1 + (size_t)col * 32 + quad * 8;   // ks-stride 8192
        f32x4 acc = (f32x4){0,0,0,0};
        #pragma unroll
        for (int ks = 0; ks < 17; ++ks)
            acc = MFMA(*(const bf16x8*)(bufA + ml * 552 + ks * 32 + quad * 8),
                       *(const bf16x8*)(wq + (size_t)ks * 8192), acc);
        const float bv = eb1[col];
        #pragma unroll
        for (int rg = 0; rg < 4; ++rg)
            bufB[(quad * 4 + rg) * 552 + 267 + col] = __float2bfloat16(eluf(acc[rg] + bv));
        // copy x -> bufB[0..266] (row w); zero pad 523..543
        #pragma unroll
        for (int j = 0; j < 5; ++j) {
            const int cc = lane + j * 64;
            if (cc < 267) bufB[w * 552 + cc] = bufA[w * 552 + cc];
        }
        if (lane < 21) bufB[w * 552 + 523 + lane] = __float2bfloat16(0.f);
    }
    __syncthreads();

    // ---- Ph2: h2 = elu([x|h1] @ We2 + eb2) -> bufB in-place = [x|h2] ----
    {
        const int col = 16 * w + ml;
        const bf16* wq = We2 + (size_t)col * 32 + quad * 8;
        f32x4 acc = (f32x4){0,0,0,0};
        #pragma unroll
        for (int ks = 0; ks < 17; ++ks)
            acc = MFMA(*(const bf16x8*)(bufB + ml * 552 + ks * 32 + quad * 8),
                       *(const bf16x8*)(wq + (size_t)ks * 8192), acc);
        __syncthreads();   // all reads of bufB done before overwrite
        const float bv = eb2[col];
        #pragma unroll
        for (int rg = 0; rg < 4; ++rg)
            bufB[(quad * 4 + rg) * 552 + 267 + col] = __float2bfloat16(eluf(acc[rg] + bv));
    }
    __syncthreads();

    // ---- Ph3: mu|lv partial-K: wave w -> col tile (w&3), k-group (w>>2) ----
    {
        const int t = w & 3, kg = w >> 2;
        const int col = 16 * t + ml;
        const int k0 = kg * 4, k1 = (kg == 3) ? 17 : kg * 4 + 4;
        const bf16* wq = Wml + (size_t)col * 32 + quad * 8;   // ks-stride 2048
        f32x4 p = (f32x4){0,0,0,0};
        #pragma unroll
        for (int u = 0; u < 5; ++u) {
            const int ks = k0 + u;
            if (ks < k1)
                p = MFMA(*(const bf16x8*)(bufB + ml * 552 + ks * 32 + quad * 8),
                         *(const bf16x8*)(wq + (size_t)ks * 2048), p);
        }
        #pragma unroll
        for (int rg = 0; rg < 4; ++rg)
            sMLp[kg][(quad * 4 + rg) * 64 + col] = p[rg];
    }
    __syncthreads();

    // ---- Ph3b: z; bufB = [z|c] (Kpad 320); bufA[0..31] = z ----
    if (tid < 512) {
        const int r = tid >> 5, l = tid & 31;
        const float m  = sMLp[0][r * 64 + l] + sMLp[1][r * 64 + l]
                       + sMLp[2][r * 64 + l] + sMLp[3][r * 64 + l] + biasCat[l];
        const float lv = sMLp[0][r * 64 + 32 + l] + sMLp[1][r * 64 + 32 + l]
                       + sMLp[2][r * 64 + 32 + l] + sMLp[3][r * 64 + 32 + l] + biasCat[32 + l];
        const int gi = (row0 + r) * LATENT + l;
        out_mu[gi] = m; out_lv[gi] = lv;
        const bf16 zb = __float2bfloat16(m + eps[gi] * expf(0.5f * lv));
        bufA[r * 552 + l] = zb;       // prefix of [z|dh1]
        bufB[r * 552 + l] = zb;       // prefix of [z|c]
        #pragma unroll
        for (int j = 0; j < 9; ++j) {
            const int col = 32 + l + j * 32;          // 32..319
            bf16 v = __float2bfloat16(0.f);
            if (col < 299) v = bufA[r * 552 + 267 + (col - 32)];   // c
            bufB[r * 552 + col] = v;
        }
    }
    __syncthreads();

    // ---- Ph5: MoE layer 0, ks-outer; gate overlapped in two chunks ----
    {
        const int col = 16 * w + ml;
        const bf16* wq = W0 + (size_t)col * 32 + quad * 8;    // (e*10+ks)-stride 8192
        f32x4 pe0 = (f32x4){0,0,0,0}, pe1 = (f32x4){0,0,0,0}, pe2 = (f32x4){0,0,0,0};
        f32x4 pe3 = (f32x4){0,0,0,0}, pe4 = (f32x4){0,0,0,0}, pe5 = (f32x4){0,0,0,0};

        // chunk A: gate g1 (waves 0-3) + experts 0-2 (ks-outer, all waves)
        if (w < 4) {
            const int gc = 16 * w + ml;
            const bf16* gq = Wg0 + (size_t)gc * 32 + quad * 8;   // ks-stride 2048
            f32x4 p = (f32x4){0,0,0,0};
            #pragma unroll
            for (int ks = 0; ks < 10; ++ks)
                p = MFMA(*(const bf16x8*)(bufB + ml * 552 + ks * 32 + quad * 8),
                         *(const bf16x8*)(gq + (size_t)ks * 2048), p);
            const float bv = gb0[gc];
            #pragma unroll
            for (int rg = 0; rg < 4; ++rg)
                sG1[(quad * 4 + rg) * 72 + gc] = __float2bfloat16(eluf(p[rg] + bv));
        }
        #pragma unroll
        for (int ks = 0; ks < 10; ++ks) {
            const bf16x8 a = *(const bf16x8*)(bufB + ml * 552 + ks * 32 + quad * 8);
            pe0 = MFMA(a, *(const bf16x8*)(wq + (size_t)(0 * 10 + ks) * 8192), pe0);
            pe1 = MFMA(a, *(const bf16x8*)(wq + (size_t)(1 * 10 + ks) * 8192), pe1);
            pe2 = MFMA(a, *(const bf16x8*)(wq + (size_t)(2 * 10 + ks) * 8192), pe2);
        }
        __syncthreads();

        // chunk B: gate g2+logits+softmax (wave 0) + experts 3-5 (ks-outer)
        if (w == 0) {
            #pragma unroll
            for (int t = 0; t < 4; ++t) {
                const int gc = 16 * t + ml;
                const bf16* gq = Wg1 + (size_t)gc * 32 + quad * 8;
                f32x4 p = (f32x4){0,0,0,0};
                #pragma unroll
                for (int ks = 0; ks < 2; ++ks)
                    p = MFMA(*(const bf16x8*)(sG1 + ml * 72 + ks * 32 + quad * 8),
                             *(const bf16x8*)(gq + (size_t)ks * 2048), p);
                const float bv = gb1[gc];
                #pragma unroll
                for (int rg = 0; rg < 4; ++rg)
                    sG2[(quad * 4 + rg) * 72 + gc] = __float2bfloat16(eluf(p[rg] + bv));
            }
            {
                const bf16* gq = Wg2 + (size_t)ml * 32 + quad * 8;   // ks-stride 1024
                f32x4 p = (f32x4){0,0,0,0};
                #pragma unroll
                for (int ks = 0; ks < 2; ++ks)
                    p = MFMA(*(const bf16x8*)(sG2 + ml * 72 + ks * 32 + quad * 8),
                             *(const bf16x8*)(gq + (size_t)ks * 1024), p);
                const float bv = (ml < EXPERTS) ? gb2[ml] : 0.f;
                #pragma unroll
                for (int rg = 0; rg < 4; ++rg)
                    sLg[(quad * 4 + rg) * 16 + ml] = p[rg] + bv;
            }
            if (lane < 16) {   // softmax (same wave -> sLg visible via lgkmcnt)
                float v[EXPERTS];
                float m = -1e30f;
                #pragma unroll
                for (int i = 0; i < EXPERTS; ++i) { v[i] = sLg[lane * 16 + i]; m = fmaxf(m, v[i]); }
                float s = 0.f;
                #pragma unroll
                for (int i = 0; i < EXPERTS; ++i) { v[i] = expf(v[i] - m); s += v[i]; }
                const float inv = 1.f / s;
                #pragma unroll
                for (int i = 0; i < EXPERTS; ++i) sCo[i * 16 + lane] = v[i] * inv;
            }
        }
        #pragma unroll
        for (int ks = 0; ks < 10; ++ks) {
            const bf16x8 a = *(const bf16x8*)(bufB + ml * 552 + ks * 32 + quad * 8);
            pe3 = MFMA(a, *(const bf16x8*)(wq + (size_t)(3 * 10 + ks) * 8192), pe3);
            pe4 = MFMA(a, *(const bf16x8*)(wq + (size_t)(4 * 10 + ks) * 8192), pe4);
            pe5 = MFMA(a, *(const bf16x8*)(wq + (size_t)(5 * 10 + ks) * 8192), pe5);
        }
        __syncthreads();   // sCo ready + all partials done

        f32x4 acc = (f32x4){0,0,0,0};
        auto blend = [&](const f32x4& p, int e) {
            const float bv = b0[e * 256 + col];
            #pragma unroll
            for (int rg = 0; rg < 4; ++rg)
                acc[rg] += sCo[e * 16 + quad * 4 + rg] * (p[rg] + bv);
        };
        blend(pe0, 0); blend(pe1, 1); blend(pe2, 2);
        blend(pe3, 3); blend(pe4, 4); blend(pe5, 5);
        #pragma unroll
        for (int rg = 0; rg < 4; ++rg)
            bufA[(quad * 4 + rg) * 552 + 32 + col] = __float2bfloat16(eluf(acc[rg]));
    }
    __syncthreads();

    // ---- Ph6: dh2 = elu(moe([z|dh1], W1, b1)), ks-outer -> bufB = [z|dh2] ----
    {
        const int col = 16 * w + ml;
        const bf16* wq = W1 + (size_t)col * 32 + quad * 8;    // (e*9+ks)-stride 8192
        f32x4 pe0 = (f32x4){0,0,0,0}, pe1 = (f32x4){0,0,0,0}, pe2 = (f32x4){0,0,0,0};
        f32x4 pe3 = (f32x4){0,0,0,0}, pe4 = (f32x4){0,0,0,0}, pe5 = (f32x4){0,0,0,0};
        #pragma unroll
        for (int ks = 0; ks < 9; ++ks) {
            const bf16x8 a = *(const bf16x8*)(bufA + ml * 552 + ks * 32 + quad * 8);
            pe0 = MFMA(a, *(const bf16x8*)(wq + (size_t)(0 * 9 + ks) * 8192), pe0);
            pe1 = MFMA(a, *(const bf16x8*)(wq + (size_t)(1 * 9 + ks) * 8192), pe1);
            pe2 = MFMA(a, *(const bf16x8*)(wq + (size_t)(2 * 9 + ks) * 8192), pe2);
            pe3 = MFMA(a, *(const bf16x8*)(wq + (size_t)(3 * 9 + ks) * 8192), pe3);
            pe4 = MFMA(a, *(const bf16x8*)(wq + (size_t)(4 * 9 + ks) * 8192), pe4);
            pe5 = MFMA(a, *(const bf16x8*)(wq + (size_t)(5 * 9 + ks) * 8192), pe5);
        }
        f32x4 acc = (f32x4){0,0,0,0};
        auto blend = [&](const f32x4& p, int e) {
            const float bv = b1[e * 256 + col];
            #pragma unroll
            for (int rg = 0; rg < 4; ++rg)
                acc[rg] += sCo[e * 16 + quad * 4 + rg] * (p[rg] + bv);
        };
        blend(pe0, 0); blend(pe1, 1); blend(pe2, 2);
        blend(pe3, 3); blend(pe4, 4); blend(pe5, 5);
        // writes to bufB; its last reads were before the Ph5-end barrier
        #pragma unroll
        for (int rg = 0; rg < 4; ++rg)
            bufB[(quad * 4 + rg) * 552 + 32 + col] = __float2bfloat16(eluf(acc[rg]));
    }
    __syncthreads();

    // ---- Ph7: out = moe([z|dh2], W2, b2), M=267 (17 tiles), ks-outer ----
    {
        for (int t = w; t < 17; t += 16) {
            const int col = 16 * t + ml;
            const bf16* wq = W2 + (size_t)col * 32 + quad * 8;   // (e*9+ks)-stride 10240
            f32x4 pe0 = (f32x4){0,0,0,0}, pe1 = (f32x4){0,0,0,0}, pe2 = (f32x4){0,0,0,0};
            f32x4 pe3 = (f32x4){0,0,0,0}, pe4 = (f32x4){0,0,0,0}, pe5 = (f32x4){0,0,0,0};
            #pragma unroll
            for (int ks = 0; ks < 9; ++ks) {
                const bf16x8 a = *(const bf16x8*)(bufB + ml * 552 + ks * 32 + quad * 8);
                pe0 = MFMA(a, *(const bf16x8*)(wq + (size_t)(0 * 9 + ks) * 10240), pe0);
                pe1 = MFMA(a, *(const bf16x8*)(wq + (size_t)(1 * 9 + ks) * 10240), pe1);
                pe2 = MFMA(a, *(const bf16x8*)(wq + (size_t)(2 * 9 + ks) * 10240), pe2);
                pe3 = MFMA(a, *(const bf16x8*)(wq + (size_t)(3 * 9 + ks) * 10240), pe3);
                pe4 = MFMA(a, *(const bf16x8*)(wq + (size_t)(4 * 9 + ks) * 10240), pe4);
                pe5 = MFMA(a, *(const bf16x8*)(wq + (size_t)(5 * 9 + ks) * 10240), pe5);
            }
            f32x4 acc = (f32x4){0,0,0,0};
            auto blend = [&](const f32x4& p, int e) {
                const float bv = (col < FRAME) ? b2[e * FRAME + col] : 0.f;
                #pragma unroll
                for (int rg = 0; rg < 4; ++rg)
                    acc[rg] += sCo[e * 16 + quad * 4 + rg] * (p[rg] + bv);
            };
            blend(pe0, 0); blend(pe1, 1); blend(pe2, 2);
            blend(pe3, 3); blend(pe4, 4); blend(pe5, 5);
            if (col < FRAME) {
                #pragma unroll
                for (int rg = 0; rg < 4; ++rg)
                    out_layer[(size_t)(row0 + quad * 4 + rg) * FRAME + col] = acc[rg];
            }
        }
    }
}

// ---------------------------------------------------------------------------
extern "C" void kernel_launch(void* const* d_in, const int* in_sizes, int n_in,
                              void* d_out, int out_size, void* d_ws, size_t ws_size,
                              hipStream_t stream) {
    const float* x       = (const float*)d_in[0];
    const float* c       = (const float*)d_in[1];
    const float* eps     = (const float*)d_in[2];
    const float* enc_w1  = (const float*)d_in[3];
    const float* enc_b1  = (const float*)d_in[4];
    const float* enc_w2  = (const float*)d_in[5];
    const float* enc_b2  = (const float*)d_in[6];
    const float* enc_wmu = (const float*)d_in[7];
    const float* enc_bmu = (const float*)d_in[8];
    const float* enc_wlv = (const float*)d_in[9];
    const float* enc_blv = (const float*)d_in[10];
    const float* g_w0    = (const float*)d_in[11];
    const float* g_b0    = (const float*)d_in[12];
    const float* g_w1    = (const float*)d_in[13];
    const float* g_b1    = (const float*)d_in[14];
    const float* g_w2    = (const float*)d_in[15];
    const float* g_b2    = (const float*)d_in[16];
    const float* w0      = (const float*)d_in[17];
    const float* b0      = (const float*)d_in[18];
    const float* w1      = (const float*)d_in[19];
    const float* b1      = (const float*)d_in[20];
    const float* w2      = (const float*)d_in[21];
    const float* b2      = (const float*)d_in[22];

    // output (f32): [layer (4096x267) | mu (4096x32) | logvar (4096x32)]
    float* out_layer = (float*)d_out;
    float* out_mu    = out_layer + (size_t)N_BATCH * FRAME;
    float* out_lv    = out_mu    + (size_t)N_BATCH * LATENT;

    // ---- workspace layout (16B-aligned): biasCat + repacked weights only ----
    char* p = (char*)d_ws;
    float* biasCat = (float*)p;  p += 64 * 4;
    bf16* Wt_e1 = (bf16*)p;      p += (size_t)17 * 256 * 32 * 2;
    bf16* Wt_e2 = (bf16*)p;      p += (size_t)17 * 256 * 32 * 2;
    bf16* Wt_ml = (bf16*)p;      p += (size_t)17 * 64 * 32 * 2;
    bf16* Wt_g0 = (bf16*)p;      p += (size_t)10 * 64 * 32 * 2;
    bf16* Wt_g1 = (bf16*)p;      p += (size_t)2 * 64 * 32 * 2;
    bf16* Wt_g2 = (bf16*)p;      p += (size_t)2 * 32 * 32 * 2;
    bf16* Wt_w0 = (bf16*)p;      p += (size_t)EXPERTS * 10 * 256 * 32 * 2;
    bf16* Wt_w1 = (bf16*)p;      p += (size_t)EXPERTS * 9 * 256 * 32 * 2;
    bf16* Wt_w2 = (bf16*)p;      p += (size_t)EXPERTS * 9 * 320 * 32 * 2;

    WTab tab;
    int cum = 0, n = 0;
    auto add = [&](const float* src, bf16* dst, int K, int M, int Mtot, int mOff, int E) {
        int Ksteps;
        if (K == 534 || K == 523) Ksteps = 17;
        else if (K == 299) Ksteps = 10;
        else if (K == 288) Ksteps = 9;
        else Ksteps = 2;   // K=64
        const int Mtiles = (M + 31) / 32;
        tab.e[n] = {src, dst, K, M, Mtot, mOff, Ksteps, Mtiles, cum};
        cum += E * Ksteps * Mtiles;
        ++n;
    };
    add(enc_w1,  Wt_e1, 534, 256, 256, 0, 1);
    add(enc_w2,  Wt_e2, 523, 256, 256, 0, 1);
    add(enc_wmu, Wt_ml, 523, 32, 64, 0, 1);
    add(enc_wlv, Wt_ml, 523, 32, 64, 32, 1);
    add(g_w0,    Wt_g0, 299, 64, 64, 0, 1);
    add(g_w1,    Wt_g1, 64, 64, 64, 0, 1);
    add(g_w2,    Wt_g2, 64, 6, 32, 0, 1);
    add(w0,      Wt_w0, 299, 256, 256, 0, EXPERTS);
    add(w1,      Wt_w1, 288, 256, 256, 0, EXPERTS);
    add(w2,      Wt_w2, 288, 267, 320, 0, EXPERTS);
    tab.total = cum;

    // 0) prep: weight repack (cum blocks) + biasCat
    prep_kernel<<<dim3(cum), dim3(256), 0, stream>>>(enc_bmu, enc_blv, biasCat, tab);

    // 1) fully fused network: 256 blocks x 1024 threads (1 block/CU, 16 waves)
    fused_kernel<<<dim3(N_BATCH / 16), dim3(1024), 0, stream>>>(
        x, c, eps,
        Wt_e1, enc_b1, Wt_e2, enc_b2, Wt_ml, biasCat,
        Wt_g0, g_b0, Wt_g1, g_b1, Wt_g2, g_b2,
        Wt_w0, b0, Wt_w1, b1, Wt_w2, b2,
        out_layer, out_mu, out_lv);
}